// Round 5
// baseline (170.977 us; speedup 1.0000x reference)
//
#include <hip/hip_runtime.h>
#include <hip/hip_bf16.h>

// QuIP#-style quantized linear. bf16 MFMA GEMM with on-the-fly codebook
// decompression. R5: (a) nt loads for the STREAMING qidxs so the 1 MB bf16
// codebook stays L2-resident (R4's gathers were missing L2 -> ~700cyc L3
// latency); (b) 32 KB LDS tile -> 4 blocks/CU = 32 waves/CU; (c) zpart
// replaced by fp32 atomic accumulation into a 1 MB z buffer.

typedef __attribute__((ext_vector_type(4))) float f32x4;
typedef __attribute__((ext_vector_type(8))) __bf16 bf16x8;
typedef __attribute__((ext_vector_type(4))) __bf16 bf16x4;
typedef __attribute__((ext_vector_type(4))) int i32x4;

#define IN_F 8192
#define OUT_F 8192
#define TOKENS 32
#define KSPLIT 16
#define KCHUNK 512
#define INV_SQRT_8192 0.011048543456039806f
#define PAD(i) ((i) + ((i) >> 5))

// ---------------- register FWHT-32 ----------------
__device__ inline void fwht32_reg(float* r) {
    #pragma unroll
    for (int h = 1; h < 32; h <<= 1)
        #pragma unroll
        for (int i = 0; i < 32; i += 2 * h)
            #pragma unroll
            for (int j = 0; j < h; ++j) {
                float a = r[i + j], b = r[i + j + h];
                r[i + j] = a + b;
                r[i + j + h] = a - b;
            }
}

// ---------------- full FWHT-8192 in padded LDS, 256 threads ----------------
__device__ inline void fwht8192_lds(float* s, int tid) {
    float r[32];
    int b1 = tid * 32;                       // pass 1: bits 0-4
    #pragma unroll
    for (int j = 0; j < 32; ++j) r[j] = s[PAD(b1 + j)];
    fwht32_reg(r);
    #pragma unroll
    for (int j = 0; j < 32; ++j) s[PAD(b1 + j)] = r[j];
    __syncthreads();
    int b2 = (tid & 31) + (tid >> 5) * 1024; // pass 2: bits 5-9
    #pragma unroll
    for (int j = 0; j < 32; ++j) r[j] = s[PAD(b2 + 32 * j)];
    fwht32_reg(r);
    #pragma unroll
    for (int j = 0; j < 32; ++j) s[PAD(b2 + 32 * j)] = r[j];
    __syncthreads();
    #pragma unroll
    for (int jj = 0; jj < 4; ++jj) {         // pass 3: bits 10-12
        float g[8];
        int b3 = tid * 4 + jj;
        #pragma unroll
        for (int k = 0; k < 8; ++k) g[k] = s[PAD(b3 + 1024 * k)];
        #pragma unroll
        for (int h = 1; h < 8; h <<= 1)
            #pragma unroll
            for (int i = 0; i < 8; i += 2 * h)
                #pragma unroll
                for (int j = 0; j < h; ++j) {
                    float a = g[i + j], b = g[i + j + h];
                    g[i + j] = a + b;
                    g[i + j + h] = a - b;
                }
        #pragma unroll
        for (int k = 0; k < 8; ++k) s[PAD(b3 + 1024 * k)] = g[k];
    }
    __syncthreads();
}

// ---------------- kernel 1: codebook cvt + input FWHT ----------------
__global__ __launch_bounds__(256)
void prep_kernel(const float* __restrict__ cb, __bf16* __restrict__ cbb,
                 const float* __restrict__ x, const float* __restrict__ su,
                 __bf16* __restrict__ xh) {
    __shared__ float s[8192 + 256];
    const int tid = threadIdx.x;
    if (blockIdx.x < 512) {
        int i = blockIdx.x * 256 + tid;
        float4 v = ((const float4*)cb)[i];
        bf16x4 o;
        o[0] = (__bf16)v.x; o[1] = (__bf16)v.y;
        o[2] = (__bf16)v.z; o[3] = (__bf16)v.w;
        ((bf16x4*)cbb)[i] = o;
        return;
    }
    const int t = blockIdx.x - 512;
    #pragma unroll
    for (int i = tid; i < IN_F; i += 256)
        s[PAD(i)] = x[t * IN_F + i] * su[i];
    __syncthreads();
    fwht8192_lds(s, tid);
    #pragma unroll
    for (int i = tid; i < IN_F; i += 256)
        xh[t * IN_F + i] = (__bf16)(s[PAD(i)] * INV_SQRT_8192);
}

// ---------------- kernel 2: z += xh @ W^T, on-the-fly decompress -----------
// 1024 blocks (64 nb x 16 ks) x 512 thr (8 waves). Block = 128 n x 512 k.
// LDS 32 KB -> 4 blocks/CU = 32 waves/CU. qidxs loads nt (stream; protect
// codebook L2 residency). Barrier-free K-loop; gathers 2 groups ahead.
// Epilogue: fp32 atomic adds into z[t][n] (z pre-zeroed via memsetAsync).
__global__ __launch_bounds__(512, 8)
void qgemm_kernel(const int* __restrict__ qidxs,
                  const __bf16* __restrict__ cb,
                  const __bf16* __restrict__ xh,
                  float* __restrict__ z) {
    __shared__ __align__(16) __bf16 xt[32 * KCHUNK];   // 32 KB
    const int ks = blockIdx.x & 15;
    const int nb = blockIdx.x >> 4;
    const int tid = threadIdx.x;
    const int wave = tid >> 6, lane = tid & 63;
    const int quad = lane >> 4, l16 = lane & 15;
    const int n = nb * 128 + wave * 16 + l16;
    const int* qrow = qidxs + (size_t)n * 1024 + ks * (KCHUNK / 8);
    const bf16x8* cbv = (const bf16x8*)cb;

    // stage xh slice -> LDS (16B chunks, row-xor swizzle)
    #pragma unroll
    for (int i = 0; i < 4; ++i) {
        int f = i * 512 + tid, r = f >> 6, c = f & 63;
        i32x4 v = *(const i32x4*)(xh + (size_t)r * IN_F + ks * KCHUNK + c * 8);
        *(i32x4*)(xt + ((r * 64 + (c ^ (r & 7))) << 3)) = v;
    }
    __syncthreads();    // the only barrier

    f32x4 acc0 = {0.f, 0.f, 0.f, 0.f};
    f32x4 acc1 = {0.f, 0.f, 0.f, 0.f};
    int idx[4][4];
    bf16x8 bfr[4][4];

    // prologue: idx groups 0..2 (nt), gathers groups 0..1
    #pragma unroll
    for (int g = 0; g < 3; ++g)
        #pragma unroll
        for (int j = 0; j < 4; ++j)
            idx[g][j] = __builtin_nontemporal_load(qrow + (g * 4 + j) * 4 + quad);
    #pragma unroll
    for (int g = 0; g < 2; ++g)
        #pragma unroll
        for (int j = 0; j < 4; ++j)
            bfr[g][j] = cbv[idx[g][j]];

    #pragma unroll
    for (int g = 0; g < 4; ++g) {
        if (g + 3 < 4) {
            #pragma unroll
            for (int j = 0; j < 4; ++j)
                idx[g + 3][j] =
                    __builtin_nontemporal_load(qrow + ((g + 3) * 4 + j) * 4 + quad);
        }
        if (g + 2 < 4) {
            #pragma unroll
            for (int j = 0; j < 4; ++j)
                bfr[g + 2][j] = cbv[idx[g + 2][j]];
        }
        #pragma unroll
        for (int j = 0; j < 4; ++j) {
            const int T = g * 4 + j;
            const int sw = (((T * 4 + quad) ^ (l16 & 7)) << 3);
            bf16x8 a0 = *(const bf16x8*)(xt + l16 * KCHUNK + sw);
            bf16x8 a1 = *(const bf16x8*)(xt + (l16 + 16) * KCHUNK + sw);
            acc0 = __builtin_amdgcn_mfma_f32_16x16x32_bf16(a0, bfr[g][j], acc0, 0, 0, 0);
            acc1 = __builtin_amdgcn_mfma_f32_16x16x32_bf16(a1, bfr[g][j], acc1, 0, 0, 0);
        }
    }

    // D[m=quad*4+r][n=l16]; accumulate into z[t][n]
    float* zp = z + n;
    #pragma unroll
    for (int r = 0; r < 4; ++r) {
        unsafeAtomicAdd(zp + (quad * 4 + r) * OUT_F, acc0[r]);
        unsafeAtomicAdd(zp + (16 + quad * 4 + r) * OUT_F, acc1[r]);
    }
}

// ------- kernel 3: phase A out-FWHT: FWHT-256 (low 8 bits) of z ------------
__global__ __launch_bounds__(256)
void zsumA_kernel(const float* __restrict__ z, float* __restrict__ ztmp) {
    __shared__ float s[1024 + 32];
    const int t = blockIdx.x >> 3, ch = blockIdx.x & 7, tid = threadIdx.x;
    float4 a = *(const float4*)(z + (size_t)t * OUT_F + ch * 1024 + tid * 4);
    s[PAD(4 * tid + 0)] = a.x; s[PAD(4 * tid + 1)] = a.y;
    s[PAD(4 * tid + 2)] = a.z; s[PAD(4 * tid + 3)] = a.w;
    __syncthreads();
    for (int h = 1; h < 256; h <<= 1) {
        #pragma unroll
        for (int b = 0; b < 2; ++b) {
            int p = tid + b * 256;               // pair 0..511
            int g = p >> 7, off = p & 127;
            int i0 = g * 256 + (((off & ~(h - 1)) << 1) | (off & (h - 1)));
            float A = s[PAD(i0)], B = s[PAD(i0 + h)];
            s[PAD(i0)] = A + B; s[PAD(i0 + h)] = A - B;
        }
        __syncthreads();
    }
    float4 o;
    o.x = s[PAD(4 * tid + 0)]; o.y = s[PAD(4 * tid + 1)];
    o.z = s[PAD(4 * tid + 2)]; o.w = s[PAD(4 * tid + 3)];
    *(float4*)(ztmp + (size_t)t * OUT_F + ch * 1024 + tid * 4) = o;
}

// ------- kernel 4: phase B out-FWHT: FWHT-32 (high 5 bits) + scale ---------
__global__ __launch_bounds__(256)
void zsumB_kernel(const float* __restrict__ ztmp, const float* __restrict__ sv,
                  const float* __restrict__ wscale, float* __restrict__ out) {
    const int t = blockIdx.x;
    const int jl = threadIdx.x;                   // 0..255
    float r[32];
    #pragma unroll
    for (int jh = 0; jh < 32; ++jh)
        r[jh] = ztmp[(size_t)t * OUT_F + jh * 256 + jl];
    fwht32_reg(r);
    const float sc = INV_SQRT_8192 * wscale[0];
    #pragma unroll
    for (int jh = 0; jh < 32; ++jh)
        out[(size_t)t * OUT_F + jh * 256 + jl] = r[jh] * sc * sv[jh * 256 + jl];
}

extern "C" void kernel_launch(void* const* d_in, const int* in_sizes, int n_in,
                              void* d_out, int out_size, void* d_ws, size_t ws_size,
                              hipStream_t stream) {
    const float* x      = (const float*)d_in[0];   // (32, 8192)
    const float* cb     = (const float*)d_in[1];   // (65536, 8)
    const int*   qidxs  = (const int*)d_in[2];     // (8192, 1024)
    const float* su     = (const float*)d_in[3];   // (8192,)
    const float* sv     = (const float*)d_in[4];   // (8192,)
    const float* wscale = (const float*)d_in[5];   // scalar
    float* out = (float*)d_out;                    // (32, 8192) fp32

    char* ws = (char*)d_ws;
    __bf16* cb_bf16 = (__bf16*)ws;                               // 1 MB
    __bf16* xh      = (__bf16*)(ws + (1u << 20));                // 512 KB
    float*  zbuf    = (float*)(ws + (1u << 20) + (512u << 10));  // 1 MB
    float*  ztmp    = (float*)(ws + (1u << 20) + (512u << 10) + (1u << 20));

    hipMemsetAsync(zbuf, 0, (size_t)TOKENS * OUT_F * 4, stream);
    hipLaunchKernelGGL(prep_kernel, dim3(544), dim3(256), 0, stream,
                       cb, cb_bf16, x, su, xh);
    hipLaunchKernelGGL(qgemm_kernel, dim3(64 * KSPLIT), dim3(512), 0, stream,
                       qidxs, cb_bf16, xh, zbuf);
    hipLaunchKernelGGL(zsumA_kernel, dim3(256), dim3(256), 0, stream,
                       zbuf, ztmp);
    hipLaunchKernelGGL(zsumB_kernel, dim3(TOKENS), dim3(256), 0, stream,
                       ztmp, sv, wscale, out);
}

// Round 6
// 138.968 us; speedup vs baseline: 1.2303x; 1.2303x over previous
//
#include <hip/hip_runtime.h>
#include <hip/hip_bf16.h>

// QuIP#-style quantized linear. R6: 32x32x16 bf16 MFMA (one MFMA covers all
// 32 tokens -> half the MFMA/ds_read/epilogue work of 16x16x32), deep
// barrier-free gather pipeline (10 tiles ahead, launch_bounds(512,4) so the
// compiler KEEPS it - R5's (512,8) VGPR=32 serialized everything), bf16
// zpart (8 MB, fits ws), fused output FWHT. Gather floor: 8.4M random 64B
// L2 line-requests / (8 XCD x 16/cyc x 2.4GHz) ~= 27 us.

typedef __attribute__((ext_vector_type(4))) float f32x4;
typedef __attribute__((ext_vector_type(16))) float f32x16;
typedef __attribute__((ext_vector_type(8))) __bf16 bf16x8;
typedef __attribute__((ext_vector_type(4))) __bf16 bf16x4;
typedef __attribute__((ext_vector_type(4))) int i32x4;

#define IN_F 8192
#define OUT_F 8192
#define TOKENS 32
#define KSPLIT 16
#define KCHUNK 512                 // k per block
#define NTILES (KCHUNK / 16)       // 32 mfma k-tiles per wave
#define NG (NTILES / 2)            // 16 groups of 2 tiles
#define DG 5                       // gather lookahead (groups)
#define DI 7                       // idx lookahead (groups)
#define CH (KCHUNK / 8)            // 64 8-elem chunks per token row in LDS
#define INV_SQRT_8192 0.011048543456039806f
#define PAD(i) ((i) + ((i) >> 5))

// ---------------- register FWHT-32 ----------------
__device__ inline void fwht32_reg(float* r) {
    #pragma unroll
    for (int h = 1; h < 32; h <<= 1)
        #pragma unroll
        for (int i = 0; i < 32; i += 2 * h)
            #pragma unroll
            for (int j = 0; j < h; ++j) {
                float a = r[i + j], b = r[i + j + h];
                r[i + j] = a + b;
                r[i + j + h] = a - b;
            }
}

// ---------------- full FWHT-8192 in padded LDS, 256 threads ----------------
__device__ inline void fwht8192_lds(float* s, int tid) {
    float r[32];
    int b1 = tid * 32;                       // pass 1: bits 0-4
    #pragma unroll
    for (int j = 0; j < 32; ++j) r[j] = s[PAD(b1 + j)];
    fwht32_reg(r);
    #pragma unroll
    for (int j = 0; j < 32; ++j) s[PAD(b1 + j)] = r[j];
    __syncthreads();
    int b2 = (tid & 31) + (tid >> 5) * 1024; // pass 2: bits 5-9
    #pragma unroll
    for (int j = 0; j < 32; ++j) r[j] = s[PAD(b2 + 32 * j)];
    fwht32_reg(r);
    #pragma unroll
    for (int j = 0; j < 32; ++j) s[PAD(b2 + 32 * j)] = r[j];
    __syncthreads();
    #pragma unroll
    for (int jj = 0; jj < 4; ++jj) {         // pass 3: bits 10-12
        float g[8];
        int b3 = tid * 4 + jj;
        #pragma unroll
        for (int k = 0; k < 8; ++k) g[k] = s[PAD(b3 + 1024 * k)];
        #pragma unroll
        for (int h = 1; h < 8; h <<= 1)
            #pragma unroll
            for (int i = 0; i < 8; i += 2 * h)
                #pragma unroll
                for (int j = 0; j < h; ++j) {
                    float a = g[i + j], b = g[i + j + h];
                    g[i + j] = a + b;
                    g[i + j + h] = a - b;
                }
        #pragma unroll
        for (int k = 0; k < 8; ++k) s[PAD(b3 + 1024 * k)] = g[k];
    }
    __syncthreads();
}

// ---------------- kernel 1: codebook cvt + input FWHT ----------------
__global__ __launch_bounds__(256)
void prep_kernel(const float* __restrict__ cb, __bf16* __restrict__ cbb,
                 const float* __restrict__ x, const float* __restrict__ su,
                 __bf16* __restrict__ xh) {
    __shared__ float s[8192 + 256];
    const int tid = threadIdx.x;
    if (blockIdx.x < 512) {
        int i = blockIdx.x * 256 + tid;
        float4 v = ((const float4*)cb)[i];
        bf16x4 o;
        o[0] = (__bf16)v.x; o[1] = (__bf16)v.y;
        o[2] = (__bf16)v.z; o[3] = (__bf16)v.w;
        ((bf16x4*)cbb)[i] = o;
        return;
    }
    const int t = blockIdx.x - 512;
    #pragma unroll
    for (int i = tid; i < IN_F; i += 256)
        s[PAD(i)] = x[t * IN_F + i] * su[i];
    __syncthreads();
    fwht8192_lds(s, tid);
    #pragma unroll
    for (int i = tid; i < IN_F; i += 256)
        xh[t * IN_F + i] = (__bf16)(s[PAD(i)] * INV_SQRT_8192);
}

// ---------------- kernel 2: zpart = xh @ W^T (bf16 partials) --------------
// 512 blocks (32 nb x 16 ks) x 512 thr (8 waves). Block = 256 n x 512 k.
// Wave = 32 n x 512 k, 32 k-tiles of 16 via mfma_f32_32x32x16_bf16:
//   A[m=lane&31][k=8*(lane>>5)+j]  (xh from LDS, xor-swizzled)
//   B[k=8*(lane>>5)+j][n=lane&31]  = one 16B codebook entry per lane
//   D[m=(reg&3)+4*(lane>>5)+8*(reg>>2)][n=lane&31]
// Barrier-free K-loop; gathers DG groups ahead, idx (i32x4 = 2 tiles) DI.
__global__ __launch_bounds__(512, 4)
void qgemm_kernel(const int* __restrict__ qidxs,
                  const __bf16* __restrict__ cb,
                  const __bf16* __restrict__ xh,
                  __bf16* __restrict__ zpart) {
    __shared__ __align__(16) __bf16 xt[TOKENS * KCHUNK];   // 32 KB
    const int ks = blockIdx.x & 15;
    const int nb = blockIdx.x >> 4;
    const int tid = threadIdx.x;
    const int wave = tid >> 6, lane = tid & 63;
    const int h = lane >> 5, lc = lane & 31;
    const int n = nb * 256 + wave * 32 + lc;

    // stage xh k-slice (32 tok x 512 k) -> LDS, 16B chunks xor-swizzled
    #pragma unroll
    for (int i = 0; i < 4; ++i) {
        int f = i * 512 + tid, r = f >> 6, c = f & 63;
        i32x4 v = *(const i32x4*)(xh + (size_t)r * IN_F + ks * KCHUNK + c * 8);
        *(i32x4*)(xt + ((r * CH + (c ^ (r & 7))) << 3)) = v;
    }
    __syncthreads();    // the only barrier

    const int* qrow = qidxs + (size_t)n * (IN_F / 8) + ks * CH;
    const bf16x8* cbv = (const bf16x8*)cb;

    f32x16 acc;
    #pragma unroll
    for (int i = 0; i < 16; ++i) acc[i] = 0.f;

    i32x4 iv[NG];
    bf16x8 bfr[NG][2];

    // prologue
    #pragma unroll
    for (int g = 0; g < DI; ++g)
        iv[g] = *(const i32x4*)(qrow + g * 4);
    #pragma unroll
    for (int g = 0; g < DG; ++g) {
        int e0 = h ? iv[g][1] : iv[g][0];
        int e1 = h ? iv[g][3] : iv[g][2];
        bfr[g][0] = cbv[e0];
        bfr[g][1] = cbv[e1];
    }

    #pragma unroll
    for (int g = 0; g < NG; ++g) {
        if (g + DI < NG)
            iv[g + DI] = *(const i32x4*)(qrow + (g + DI) * 4);
        if (g + DG < NG) {
            int e0 = h ? iv[g + DG][1] : iv[g + DG][0];
            int e1 = h ? iv[g + DG][3] : iv[g + DG][2];
            bfr[g + DG][0] = cbv[e0];
            bfr[g + DG][1] = cbv[e1];
        }
        #pragma unroll
        for (int s = 0; s < 2; ++s) {
            const int T = 2 * g + s;
            bf16x8 a = *(const bf16x8*)(xt +
                          ((lc * CH + ((2 * T + h) ^ (lc & 7))) << 3));
            acc = __builtin_amdgcn_mfma_f32_32x32x16_bf16(a, bfr[g][s], acc,
                                                          0, 0, 0);
        }
    }

    // epilogue: bf16 partials
    __bf16* zp = zpart + ((size_t)ks * TOKENS) * OUT_F + n;
    #pragma unroll
    for (int r = 0; r < 16; ++r) {
        int m = (r & 3) + 4 * h + 8 * (r >> 2);
        zp[(size_t)m * OUT_F] = (__bf16)acc[r];
    }
}

// ------- kernel 3: out = fwht(sum_ks zpart)/sqrt(n) * SV * Wscale ----------
__global__ __launch_bounds__(256)
void zsum_kernel(const __bf16* __restrict__ zpart, const float* __restrict__ sv,
                 const float* __restrict__ wscale, float* __restrict__ out) {
    __shared__ float s[8192 + 256];
    const int t = blockIdx.x, tid = threadIdx.x;
    #pragma unroll
    for (int cc = 0; cc < 4; ++cc) {
        int col = cc * 2048 + tid * 8;
        float a[8] = {0.f, 0.f, 0.f, 0.f, 0.f, 0.f, 0.f, 0.f};
        #pragma unroll
        for (int ks = 0; ks < KSPLIT; ++ks) {
            bf16x8 v = *(const bf16x8*)(zpart +
                         ((size_t)(ks * TOKENS + t)) * OUT_F + col);
            #pragma unroll
            for (int j = 0; j < 8; ++j) a[j] += (float)v[j];
        }
        #pragma unroll
        for (int j = 0; j < 8; ++j) s[PAD(col + j)] = a[j];
    }
    __syncthreads();
    fwht8192_lds(s, tid);
    const float sc = INV_SQRT_8192 * wscale[0];
    #pragma unroll
    for (int i = tid; i < OUT_F; i += 256)
        out[t * OUT_F + i] = s[PAD(i)] * sc * sv[i];
}

extern "C" void kernel_launch(void* const* d_in, const int* in_sizes, int n_in,
                              void* d_out, int out_size, void* d_ws, size_t ws_size,
                              hipStream_t stream) {
    const float* x      = (const float*)d_in[0];   // (32, 8192)
    const float* cb     = (const float*)d_in[1];   // (65536, 8)
    const int*   qidxs  = (const int*)d_in[2];     // (8192, 1024)
    const float* su     = (const float*)d_in[3];   // (8192,)
    const float* sv     = (const float*)d_in[4];   // (8192,)
    const float* wscale = (const float*)d_in[5];   // scalar
    float* out = (float*)d_out;                    // (32, 8192) fp32

    char* ws = (char*)d_ws;
    __bf16* cb_bf16 = (__bf16*)ws;                               // 1 MB
    __bf16* xh      = (__bf16*)(ws + (1u << 20));                // 512 KB
    __bf16* zpart   = (__bf16*)(ws + (1u << 20) + (512u << 10)); // 8 MB bf16

    hipLaunchKernelGGL(prep_kernel, dim3(544), dim3(256), 0, stream,
                       cb, cb_bf16, x, su, xh);
    hipLaunchKernelGGL(qgemm_kernel, dim3(32 * KSPLIT), dim3(512), 0, stream,
                       qidxs, cb_bf16, xh, zpart);
    hipLaunchKernelGGL(zsum_kernel, dim3(TOKENS), dim3(256), 0, stream,
                       zpart, sv, wscale, out);
}